// Round 1
// baseline (4238.800 us; speedup 1.0000x reference)
//
#include <hip/hip_runtime.h>
#include <cstdint>
#include <cstddef>
#include <cmath>

// ---------------------------------------------------------------------------
// Pipeline (all data-dependent sizing handled by in-kernel guards; launches
// are static so graph capture is safe):
//   A  k_cumsum : exact sequential float32 cumsums (transposed layout)
//   B  k_diffs  : exact numpy-pairwise variance->diffs per position
//   C  k_hist1/k_sel_hi/k_hist2/k_sel_lo : exact top-32768 radix select
//   D  k_keep   : keep flags with stable tie ranks + forced T-multiples
//   E  k_segment: per-batch boundary lists + frame->segment map
//   F  k_prefix : ragged row offsets
//   G  k_pool   : segment means (comp)
//   H  k_gi     : gi = comp @ W_ih^T + b_ih (+b_hh for r,z)  [fp32 GEMM]
//   I  k_gru    : sequential GRU, one block/batch, W_hh f16 in VGPRs
//   J  k_scatter: out[b,t,:] = gru_out[b, seg(t), :]
// ---------------------------------------------------------------------------

#define NPOS 65537
#define KSEL 32768u
#define CS_STRIDE 65540   // padded row stride (floats) -> float4-aligned rows
#define MAXROWS 32832     // capacity for ragged segment rows (actual <= 32830)

typedef _Float16 f16x2 __attribute__((ext_vector_type(2)));

#if defined(__has_builtin)
#if __has_builtin(__builtin_amdgcn_fdot2)
#define HAVE_FDOT2 1
#endif
#endif

__device__ __forceinline__ float fdot2f(f16x2 a, f16x2 b, float c) {
#ifdef HAVE_FDOT2
  return __builtin_amdgcn_fdot2(a, b, c, false);
#else
  c += (float)a.x * (float)b.x;
  c += (float)a.y * (float)b.y;
  return c;
#endif
}

// --------------------------- A: exact cumsums ------------------------------
// 512 independent sequential chains: g<256 -> cs1 col j ; g>=256 -> cs2 col j
// Stored transposed: cs[j*CS_STRIDE + p], p = 0..65536. Must match numpy's
// sequential float32 rounding exactly -> fp contract OFF.
__global__ __launch_bounds__(64) void k_cumsum(const float* __restrict__ x,
                                               float* __restrict__ cs1,
                                               float* __restrict__ cs2) {
#pragma clang fp contract(off)
  int g = blockIdx.x * 64 + threadIdx.x;  // 0..511
  int j = g & 255;
  int which = g >> 8;
  float* dst = (which ? cs2 : cs1) + (size_t)j * CS_STRIDE;
  const float* xp = x + j;
  float c = 0.f, a0 = 0.f, a1, a2, a3;
  for (int p0 = 1; p0 <= 65533; p0 += 4) {
    size_t base = (size_t)(p0 - 1) * 256;
    float e0 = xp[base];
    float e1 = xp[base + 256];
    float e2 = xp[base + 512];
    float e3 = xp[base + 768];
    if (which) { e0 = e0 * e0; e1 = e1 * e1; e2 = e2 * e2; e3 = e3 * e3; }
    c = c + e0; a1 = c;
    c = c + e1; a2 = c;
    c = c + e2; a3 = c;
    float4 st; st.x = a0; st.y = a1; st.z = a2; st.w = a3;
    *reinterpret_cast<float4*>(dst + (p0 - 1)) = st;  // covers p0-1 .. p0+2
    c = c + e3; a0 = c;
  }
  dst[65536] = a0;
}

// --------------------------- B: exact diffs --------------------------------
// diffs[p] = sqrt(max(mean_j( s2/2 - (s1/2)^2 ), 0)) with numpy's pairwise
// mean order (two 128-blocks, 8 accumulators). Sentinels 1e10 at ends.
__global__ __launch_bounds__(64) void k_diffs(const float* __restrict__ cs1,
                                              const float* __restrict__ cs2,
                                              float* __restrict__ diffs) {
#pragma clang fp contract(off)
  int p = blockIdx.x * 64 + threadIdx.x;
  if (p >= NPOS) return;
  if (p == 0 || p == NPOS - 1) { diffs[p] = 1e10f; return; }
  const float* c1 = cs1 + (p - 1);
  const float* c2 = cs2 + (p - 1);
  float blk[2];
  for (int half = 0; half < 2; ++half) {
    float r[8];
#pragma unroll
    for (int t = 0; t < 8; ++t) {
      size_t off = (size_t)(half * 128 + t) * CS_STRIDE;
      float s1 = c1[off + 2] - c1[off];
      float s2 = c2[off + 2] - c2[off];
      float t1 = s1 * 0.5f;
      float u = s2 * 0.5f;
      r[t] = u - t1 * t1;
    }
    for (int i = 1; i < 16; ++i) {
#pragma unroll
      for (int t = 0; t < 8; ++t) {
        size_t off = (size_t)(half * 128 + i * 8 + t) * CS_STRIDE;
        float s1 = c1[off + 2] - c1[off];
        float s2 = c2[off + 2] - c2[off];
        float t1 = s1 * 0.5f;
        float u = s2 * 0.5f;
        r[t] += u - t1 * t1;
      }
    }
    blk[half] = ((r[0] + r[1]) + (r[2] + r[3])) + ((r[4] + r[5]) + (r[6] + r[7]));
  }
  float mean = (blk[0] + blk[1]) / 256.0f;
  float mx = mean > 0.0f ? mean : 0.0f;       // np.maximum(var, 0.0)
  diffs[p] = (float)::sqrt((double)mx);       // correctly-rounded f32 sqrt
}

// --------------------------- C: radix select -------------------------------
__global__ void k_hist1(const float* __restrict__ diffs, unsigned* __restrict__ h1) {
  int p = blockIdx.x * 256 + threadIdx.x;
  if (p >= NPOS) return;
  unsigned key = __float_as_uint(diffs[p]);   // all keys are non-negative floats
  atomicAdd(&h1[key >> 16], 1u);
}

__global__ void k_sel_hi(const unsigned* __restrict__ h1, unsigned* __restrict__ meta) {
  __shared__ unsigned loc[256];
  int t = threadIdx.x;
  unsigned s = 0;
  for (int i = 0; i < 256; ++i) s += h1[t * 256 + i];
  loc[t] = s;
  __syncthreads();
  if (t == 0) {
    unsigned run = 0; int tt = 255;
    for (; tt > 0; --tt) { if (run + loc[tt] >= KSEL) break; run += loc[tt]; }
    unsigned r2 = run;
    for (int i = 255; i >= 0; --i) {
      unsigned c = h1[tt * 256 + i];
      if (r2 + c >= KSEL) { meta[0] = (unsigned)(tt * 256 + i); meta[1] = r2; break; }
      r2 += c;
    }
  }
}

__global__ void k_hist2(const float* __restrict__ diffs, const unsigned* __restrict__ meta,
                        unsigned* __restrict__ h2) {
  int p = blockIdx.x * 256 + threadIdx.x;
  if (p >= NPOS) return;
  unsigned key = __float_as_uint(diffs[p]);
  if ((key >> 16) == meta[0]) atomicAdd(&h2[key & 0xffffu], 1u);
}

__global__ void k_sel_lo(const unsigned* __restrict__ h2, unsigned* __restrict__ meta) {
  __shared__ unsigned loc[256];
  int t = threadIdx.x;
  unsigned s = 0;
  for (int i = 0; i < 256; ++i) s += h2[t * 256 + i];
  loc[t] = s;
  __syncthreads();
  if (t == 0) {
    unsigned remaining = KSEL - meta[1];
    unsigned run = 0; int tt = 255;
    for (; tt > 0; --tt) { if (run + loc[tt] >= remaining) break; run += loc[tt]; }
    unsigned r2 = run;
    for (int i = 255; i >= 0; --i) {
      unsigned c = h2[tt * 256 + i];
      if (r2 + c >= remaining) {
        meta[2] = (meta[0] << 16) | (unsigned)(tt * 256 + i);  // K*
        meta[3] = remaining - r2;                              // need among ==K*
        break;
      }
      r2 += c;
    }
  }
}

// --------------------------- D: keep flags ---------------------------------
// Single wave: sequential chunks give exact stable tie ranks (lower index
// wins), matching argsort(-diffs, stable)[:k]. Forced multiples of T added.
__global__ __launch_bounds__(64) void k_keep(const float* __restrict__ diffs,
                                             const unsigned* __restrict__ meta,
                                             unsigned char* __restrict__ keep) {
  int lane = threadIdx.x;
  unsigned Kstar = meta[2], need = meta[3];
  unsigned base = 0;
  for (int it = 0; it < 1025; ++it) {
    int p = it * 64 + lane;
    bool valid = p < NPOS;
    unsigned key = valid ? __float_as_uint(diffs[p]) : 0u;
    bool eq = valid && (key == Kstar);
    unsigned long long m = __ballot(eq);
    unsigned rank = base + (unsigned)__popcll(m & ((1ull << lane) - 1ull));
    bool k = valid && ((key > Kstar) || (eq && rank < need) || ((p & 1023) == 0));
    if (valid) keep[p] = (unsigned char)k;
    base += (unsigned)__popcll(m);
  }
}

// --------------------------- E: per-batch segments -------------------------
__global__ __launch_bounds__(1024) void k_segment(const unsigned char* __restrict__ keep,
                                                  int* __restrict__ segid,
                                                  int* __restrict__ bnd,
                                                  int* __restrict__ nseg) {
  __shared__ int s[1024];
  int b = blockIdx.x, t = threadIdx.x;
  int f = (t >= 1) ? (int)keep[b * 1024 + t] : 0;
  s[t] = f;
  __syncthreads();
  for (int off = 1; off < 1024; off <<= 1) {
    int v = s[t];
    int add = (t >= off) ? s[t - off] : 0;
    __syncthreads();
    s[t] = v + add;
    __syncthreads();
  }
  int sc = s[t];                 // inclusive scan of interior-boundary flags
  segid[b * 1024 + t] = sc;      // frame t -> segment index
  if (f) bnd[b * 1026 + sc] = t;
  if (t == 0) bnd[b * 1026] = 0;
  if (t == 1023) {
    int m = sc + 1;
    nseg[b] = m;
    bnd[b * 1026 + m] = 1024;
  }
}

__global__ __launch_bounds__(64) void k_prefix(const int* __restrict__ nseg,
                                               int* __restrict__ pref) {
  int lane = threadIdx.x;  // 64 lanes
  int s = nseg[lane];
  for (int off = 1; off < 64; off <<= 1) {
    int u = __shfl_up(s, off);
    if (lane >= off) s += u;
  }
  pref[lane + 1] = s;
  if (lane == 0) pref[0] = 0;
}

// --------------------------- G: segment means ------------------------------
__global__ __launch_bounds__(256) void k_pool(const float* __restrict__ x,
                                              const int* __restrict__ bnd,
                                              const int* __restrict__ nseg,
                                              const int* __restrict__ pref,
                                              float* __restrict__ comp) {
  int l = blockIdx.x, b = blockIdx.y, d = threadIdx.x;
  if (l >= nseg[b]) return;
  int s = bnd[b * 1026 + l], e = bnd[b * 1026 + l + 1];
  float acc = 0.f;
  for (int t = s; t < e; ++t) acc += x[((size_t)b * 1024 + t) * 256 + d];
  comp[((size_t)pref[b] + l) * 256 + d] = acc / (float)(e - s);
}

// --------------------------- H: gi GEMM (fp32) -----------------------------
// gi[r, c] = comp[r,:] . W_ih[c,:] + b_ih[c] + (c<512 ? b_hh[c] : 0)
// BM=64, BN=128, BK=64; B staged transposed with padded stride 132.
__global__ __launch_bounds__(256) void k_gi(const float* __restrict__ comp,
                                            const float* __restrict__ Wih,
                                            const float* __restrict__ bih,
                                            const float* __restrict__ bhh,
                                            const int* __restrict__ pref,
                                            float* __restrict__ gi) {
  int total = pref[64];
  int r0 = blockIdx.x * 64;
  if (r0 >= total) return;
  int c0 = blockIdx.y * 128;
  __shared__ float As[64][64];
  __shared__ float Bs[64 * 132];
  int tid = threadIdx.x;
  int rg = tid >> 5, cl = tid & 31;
  float acc[8][4];
#pragma unroll
  for (int i = 0; i < 8; ++i)
#pragma unroll
    for (int q = 0; q < 4; ++q) acc[i][q] = 0.f;

  for (int k0 = 0; k0 < 256; k0 += 64) {
#pragma unroll
    for (int i = 0; i < 4; ++i) {
      int idx = tid + i * 256;
      int row = idx >> 4, kq = idx & 15;
      int rr = r0 + row;
      float4 v;
      if (rr < total) v = *reinterpret_cast<const float4*>(comp + (size_t)rr * 256 + k0 + kq * 4);
      else { v.x = 0.f; v.y = 0.f; v.z = 0.f; v.w = 0.f; }
      *reinterpret_cast<float4*>(&As[row][kq * 4]) = v;
    }
#pragma unroll
    for (int i = 0; i < 8; ++i) {
      int idx = tid + i * 256;
      int row = idx >> 4, kq = idx & 15;  // row 0..127 = output col offset
      float4 v = *reinterpret_cast<const float4*>(Wih + (size_t)(c0 + row) * 256 + k0 + kq * 4);
      Bs[(kq * 4 + 0) * 132 + row] = v.x;
      Bs[(kq * 4 + 1) * 132 + row] = v.y;
      Bs[(kq * 4 + 2) * 132 + row] = v.z;
      Bs[(kq * 4 + 3) * 132 + row] = v.w;
    }
    __syncthreads();
#pragma unroll 4
    for (int k = 0; k < 64; ++k) {
      float a[8], bv[4];
#pragma unroll
      for (int i = 0; i < 8; ++i) a[i] = As[rg * 8 + i][k];
#pragma unroll
      for (int q = 0; q < 4; ++q) bv[q] = Bs[k * 132 + cl + 32 * q];
#pragma unroll
      for (int i = 0; i < 8; ++i)
#pragma unroll
        for (int q = 0; q < 4; ++q) acc[i][q] += a[i] * bv[q];
    }
    __syncthreads();
  }
#pragma unroll
  for (int q = 0; q < 4; ++q) {
    int c = c0 + cl + 32 * q;
    float bias = bih[c] + (c < 512 ? bhh[c] : 0.f);
#pragma unroll
    for (int i = 0; i < 8; ++i) {
      int rr = r0 + rg * 8 + i;
      if (rr < total) gi[(size_t)rr * 768 + c] = acc[i][q] + bias;
    }
  }
}

// --------------------------- I: GRU ----------------------------------------
// One block per batch, 512 threads (8 waves, <=256 VGPR).
// Thread t holds W_hh row t (gates r/z) as 128 f16x2 VGPRs, plus half of
// n-gate row 512+(t>>1) as 64 f16x2 VGPRs. h kept in LDS (f16 pairs + fp32).
__global__ __launch_bounds__(512, 2) void k_gru(const float* __restrict__ gi,
                                                const float* __restrict__ Whh,
                                                const float* __restrict__ bhh,
                                                const int* __restrict__ nseg,
                                                const int* __restrict__ pref,
                                                float* __restrict__ gout) {
  int b = blockIdx.x;
  int t = threadIdx.x;
  int m = nseg[b];
  size_t base = (size_t)pref[b];

  f16x2 wf[128];
#pragma unroll
  for (int i = 0; i < 64; ++i) {
    float4 v = *reinterpret_cast<const float4*>(Whh + (size_t)t * 256 + i * 4);
    f16x2 lo; lo.x = (_Float16)v.x; lo.y = (_Float16)v.y;
    f16x2 hi; hi.x = (_Float16)v.z; hi.y = (_Float16)v.w;
    wf[2 * i] = lo; wf[2 * i + 1] = hi;
  }
  int nrow = 512 + (t >> 1);
  int koff = (t & 1) * 128;
  f16x2 wh[64];
#pragma unroll
  for (int i = 0; i < 32; ++i) {
    float4 v = *reinterpret_cast<const float4*>(Whh + (size_t)nrow * 256 + koff + i * 4);
    f16x2 lo; lo.x = (_Float16)v.x; lo.y = (_Float16)v.y;
    f16x2 hi; hi.x = (_Float16)v.z; hi.y = (_Float16)v.w;
    wh[2 * i] = lo; wh[2 * i + 1] = hi;
  }

  __shared__ f16x2 h2buf[128];
  __shared__ float hf[256];
  __shared__ float sg[512];
  __shared__ float pn[512];

  float bn = (t < 256) ? bhh[512 + t] : 0.f;
  if (t < 128) ((unsigned*)h2buf)[t] = 0u;
  if (t < 256) hf[t] = 0.f;
  __syncthreads();

  int hb = koff >> 1;  // 0 or 64: f16x2 index base for the half-row dot

  for (int l = 0; l < m; ++l) {
    const float* girow = gi + (base + l) * 768;
    float gv = girow[t];
    float gn = (t < 256) ? girow[512 + t] : 0.f;

    float af0 = 0.f, af1 = 0.f;
#pragma unroll
    for (int i = 0; i < 64; ++i) {
      af0 = fdot2f(wf[2 * i],     h2buf[2 * i],     af0);
      af1 = fdot2f(wf[2 * i + 1], h2buf[2 * i + 1], af1);
    }
    float af = af0 + af1;
    float ah0 = 0.f, ah1 = 0.f;
#pragma unroll
    for (int i = 0; i < 32; ++i) {
      ah0 = fdot2f(wh[2 * i],     h2buf[hb + 2 * i],     ah0);
      ah1 = fdot2f(wh[2 * i + 1], h2buf[hb + 2 * i + 1], ah1);
    }
    float ah = ah0 + ah1;

    sg[t] = 1.f / (1.f + expf(-(gv + af)));  // r (t<256) / z (256<=t<512)
    pn[t] = ah;                               // n-gate partial
    __syncthreads();
    if (t < 256) {
      float r = sg[t], z = sg[256 + t];
      float hn = pn[2 * t] + pn[2 * t + 1] + bn;
      float n = tanhf(gn + r * hn);
      float hnew = (1.f - z) * n + z * hf[t];
      hf[t] = hnew;
      ((_Float16*)h2buf)[t] = (_Float16)hnew;
      gout[(base + l) * 256 + t] = hnew;
    }
    __syncthreads();
  }
}

// --------------------------- J: scatter ------------------------------------
__global__ __launch_bounds__(256) void k_scatter(const float* __restrict__ gout,
                                                 const int* __restrict__ segid,
                                                 const int* __restrict__ pref,
                                                 float* __restrict__ out) {
  int t = blockIdx.x, b = blockIdx.y, d = threadIdx.x;
  int l = segid[b * 1024 + t];
  out[((size_t)b * 1024 + t) * 256 + d] = gout[((size_t)pref[b] + l) * 256 + d];
}

// ---------------------------------------------------------------------------
extern "C" void kernel_launch(void* const* d_in, const int* in_sizes, int n_in,
                              void* d_out, int out_size, void* d_ws, size_t ws_size,
                              hipStream_t stream) {
  const float* x   = (const float*)d_in[0];
  const float* Wih = (const float*)d_in[1];
  const float* Whh = (const float*)d_in[2];
  const float* bih = (const float*)d_in[3];
  const float* bhh = (const float*)d_in[4];
  float* out = (float*)d_out;
  char* w = (char*)d_ws;

  // ws layout (bytes); comp/gout reuse the cumsum regions (dead after k_diffs)
  const size_t o_cs1   = 0;            // 67,112,960
  const size_t o_cs2   = 67112960;     // 67,112,960
  const size_t o_diffs = 134225920;    // 262,400
  const size_t o_h1    = 134488320;    // 262,144
  const size_t o_h2    = 134750464;    // 262,144
  const size_t o_meta  = 135012608;    // 256
  const size_t o_keep  = 135012864;    // 65,792
  const size_t o_segid = 135078656;    // 262,144
  const size_t o_bnd   = 135340800;    // 262,656
  const size_t o_nseg  = 135603456;    // 256
  const size_t o_pref  = 135603712;    // 512
  const size_t o_gi    = 135604224;    // 100,859,904
  const size_t NEED    = 236464128;
  if (ws_size < NEED) return;  // visible failure rather than corruption

  float* cs1 = (float*)(w + o_cs1);
  float* cs2 = (float*)(w + o_cs2);
  float* diffs = (float*)(w + o_diffs);
  unsigned* h1 = (unsigned*)(w + o_h1);
  unsigned* h2 = (unsigned*)(w + o_h2);
  unsigned* meta = (unsigned*)(w + o_meta);
  unsigned char* keep = (unsigned char*)(w + o_keep);
  int* segid = (int*)(w + o_segid);
  int* bnd = (int*)(w + o_bnd);
  int* nseg = (int*)(w + o_nseg);
  int* pref = (int*)(w + o_pref);
  float* gi = (float*)(w + o_gi);
  float* comp = cs1;  // reuse
  float* gout = cs2;  // reuse

  hipMemsetAsync(h1, 0, 262144, stream);
  hipMemsetAsync(h2, 0, 262144, stream);

  k_cumsum <<<dim3(8),        dim3(64),   0, stream>>>(x, cs1, cs2);
  k_diffs  <<<dim3(1025),     dim3(64),   0, stream>>>(cs1, cs2, diffs);
  k_hist1  <<<dim3(257),      dim3(256),  0, stream>>>(diffs, h1);
  k_sel_hi <<<dim3(1),        dim3(256),  0, stream>>>(h1, meta);
  k_hist2  <<<dim3(257),      dim3(256),  0, stream>>>(diffs, meta, h2);
  k_sel_lo <<<dim3(1),        dim3(256),  0, stream>>>(h2, meta);
  k_keep   <<<dim3(1),        dim3(64),   0, stream>>>(diffs, meta, keep);
  k_segment<<<dim3(64),       dim3(1024), 0, stream>>>(keep, segid, bnd, nseg);
  k_prefix <<<dim3(1),        dim3(64),   0, stream>>>(nseg, pref);
  k_pool   <<<dim3(1024, 64), dim3(256),  0, stream>>>(x, bnd, nseg, pref, comp);
  k_gi     <<<dim3(513, 6),   dim3(256),  0, stream>>>(comp, Wih, bih, bhh, pref, gi);
  k_gru    <<<dim3(64),       dim3(512),  0, stream>>>(gi, Whh, bhh, nseg, pref, gout);
  k_scatter<<<dim3(1024, 64), dim3(256),  0, stream>>>(gout, segid, pref, out);
}